// Round 11
// baseline (194.398 us; speedup 1.0000x reference)
//
#include <hip/hip_runtime.h>
#include <hip/hip_fp16.h>
#include <math.h>

#define BB 2
#define NN 2048
#define NP1 2049
#define DM 128
#define NH 8
#define DK 16
#define RWIN 4
#define GRID_W 64
#define QPB 8        /* queries per block (phase 2) */
#define CAND_PQ 160  /* per-query candidate cap; binom mean ~36, sd ~6 */
#define NBLK 512     /* grid: co-resident (2/CU needed, 4/CU LDS capacity) */
#define NTILE 513    /* qkv row-tiles of 8 over 4098 rows */

__device__ __forceinline__ void unpack8(uint4 r, float* f) {
    float2 t;
    t = __half22float2(*(const __half2*)&r.x); f[0] = t.x; f[1] = t.y;
    t = __half22float2(*(const __half2*)&r.y); f[2] = t.x; f[3] = t.y;
    t = __half22float2(*(const __half2*)&r.z); f[4] = t.x; f[5] = t.y;
    t = __half22float2(*(const __half2*)&r.w); f[6] = t.x; f[7] = t.y;
}

// Fused: QKV projection (phase 1) -> manual grid barrier -> sparse local
// attention + out-projection (phase 2). The neighbor scan and all input-only
// staging run BEFORE the barrier to overlap the spin. K/V stored fp16.
// All 512 blocks are co-resident (capacity arithmetic above), so the
// arrive-and-spin barrier cannot deadlock. No-max softmax: logits are O(0.3).

__global__ __launch_bounds__(256, 2) void fused_kernel(
    const float* __restrict__ z, const float* __restrict__ patch,
    const float* __restrict__ Wq, const float* __restrict__ bq,
    const float* __restrict__ Wk, const float* __restrict__ bk,
    const float* __restrict__ Wv, const float* __restrict__ bv,
    const int* __restrict__ positions, const float* __restrict__ alive,
    const float* __restrict__ rel_bias, const float* __restrict__ Wo,
    const float* __restrict__ bo,
    float* __restrict__ q, __half* __restrict__ k, __half* __restrict__ v,
    int* __restrict__ bar, float* __restrict__ out) {
    const int tid = threadIdx.x;

    __shared__ float zrow[8][DM];
    __shared__ float sbias[NH * 81];
    __shared__ int   spx[QPB], spy[QPB];
    __shared__ float sal[QPB];
    __shared__ int   mcount[QPB];
    __shared__ int   cand[QPB][CAND_PQ];
    __shared__ float po[QPB * 4][DM + 1];
    __shared__ float pl[QPB * 4][NH + 1];
    __shared__ float srow[QPB][DM + 1];

    // ---------------- phase 1: QKV for row-tiles blockIdx, blockIdx+512 ----------------
    {
        const int cg = tid & 31;   // cols cg*4..cg*4+3
        const int rs = tid >> 5;   // row slot 0..7
        const int NROWS = BB * NP1;
        for (int tile = blockIdx.x; tile < NTILE; tile += NBLK) {
            __syncthreads(); // zrow reuse guard (cheap first pass)
            {   // stage 8 rows x 128 cols as one float4 per thread
                int r = tid >> 5, c4 = tid & 31;
                int row = tile * 8 + r;
                float4 val = make_float4(0.f, 0.f, 0.f, 0.f);
                if (row < NROWS) {
                    int b = row / NP1, ti = row % NP1;
                    const float* src = (ti < NN) ? (z + ((size_t)b * NN + ti) * DM)
                                                 : (patch + (size_t)b * DM);
                    val = ((const float4*)src)[c4];
                }
                *((float4*)&zrow[r][c4 * 4]) = val;
            }
            __syncthreads();
            float aqx = 0.f, aqy = 0.f, aqz = 0.f, aqw = 0.f;
            float akx = 0.f, aky = 0.f, akz = 0.f, akw = 0.f;
            float avx = 0.f, avy = 0.f, avz = 0.f, avw = 0.f;
#pragma unroll 4
            for (int kk = 0; kk < DM; ++kk) {
                float4 wq4 = *((const float4*)(Wq + kk * DM + cg * 4));
                float4 wk4 = *((const float4*)(Wk + kk * DM + cg * 4));
                float4 wv4 = *((const float4*)(Wv + kk * DM + cg * 4));
                float z0 = zrow[rs][kk];
                aqx = fmaf(z0, wq4.x, aqx); aqy = fmaf(z0, wq4.y, aqy);
                aqz = fmaf(z0, wq4.z, aqz); aqw = fmaf(z0, wq4.w, aqw);
                akx = fmaf(z0, wk4.x, akx); aky = fmaf(z0, wk4.y, aky);
                akz = fmaf(z0, wk4.z, akz); akw = fmaf(z0, wk4.w, akw);
                avx = fmaf(z0, wv4.x, avx); avy = fmaf(z0, wv4.y, avy);
                avz = fmaf(z0, wv4.z, avz); avw = fmaf(z0, wv4.w, avw);
            }
            int row = tile * 8 + rs;
            if (row < NROWS) {
                int b = row / NP1, ti = row % NP1;
                float4 bq4 = ((const float4*)bq)[cg];
                float4 bk4 = ((const float4*)bk)[cg];
                float4 bv4 = ((const float4*)bv)[cg];
                if (ti < NN) {
                    float4 oq = make_float4(aqx + bq4.x, aqy + bq4.y, aqz + bq4.z, aqw + bq4.w);
                    ((float4*)(q + ((size_t)b * NN + ti) * DM))[cg] = oq;
                }
                {
                    __half2 p0 = __floats2half2_rn(akx + bk4.x, aky + bk4.y);
                    __half2 p1 = __floats2half2_rn(akz + bk4.z, akw + bk4.w);
                    uint2 st; st.x = *(unsigned int*)&p0; st.y = *(unsigned int*)&p1;
                    ((uint2*)(k + ((size_t)b * NP1 + ti) * DM))[cg] = st;
                }
                {
                    __half2 p0 = __floats2half2_rn(avx + bv4.x, avy + bv4.y);
                    __half2 p1 = __floats2half2_rn(avz + bv4.z, avw + bv4.w);
                    uint2 st; st.x = *(unsigned int*)&p0; st.y = *(unsigned int*)&p1;
                    ((uint2*)(v + ((size_t)b * NP1 + ti) * DM))[cg] = st;
                }
            }
        }
    }

    // ---------------- input-only staging + neighbor scan (overlaps barrier) ----------------
    const int r0 = blockIdx.x * QPB;  // query base; same batch (NN % QPB == 0)
    const int b = r0 >> 11;
    __syncthreads(); // phase-1 LDS done before reusing nothing; orders mcount init below
    if (tid < QPB) {
        mcount[tid] = 0;
        int gbi = r0 + tid;
        spx[tid] = positions[gbi * 2 + 0];
        spy[tid] = positions[gbi * 2 + 1];
        sal[tid] = alive[gbi];
    }
    for (int t = tid; t < NH * 81; t += 256) sbias[t] = rel_bias[t];
    __syncthreads();

    int qx[QPB], qy[QPB], qi[QPB];
    float qa[QPB];
#pragma unroll
    for (int u = 0; u < QPB; ++u) {
        qx[u] = spx[u]; qy[u] = spy[u]; qa[u] = sal[u];
        qi[u] = (r0 + u) & (NN - 1);
    }
    {
        const int2* pb = (const int2*)(positions + (size_t)b * NN * 2);
        const float* ab = alive + (size_t)b * NN;
#pragma unroll
        for (int u = 0; u < NN / 256; ++u) {
            int j = u * 256 + tid;
            int2 pj = pb[j];
            float aj = ab[j];
            if (aj > 0.5f) {
                int packed = j | (pj.x << 16) | (pj.y << 24);
#pragma unroll
                for (int qn = 0; qn < QPB; ++qn) {
                    int dx = pj.x - qx[qn]; dx = dx < 0 ? -dx : dx;
                    int dy = pj.y - qy[qn]; dy = dy < 0 ? -dy : dy;
                    int ch = dx > dy ? dx : dy;
                    if (ch <= RWIN && j != qi[qn] && qa[qn] > 0.5f) {
                        int slot = atomicAdd(&mcount[qn], 1);
                        if (slot < CAND_PQ) cand[qn][slot] = packed;
                    }
                }
            }
        }
    }

    // ---------------- manual grid barrier (all blocks co-resident) ----------------
    if (tid == 0) {
        __threadfence();             // release: drain K/V/q writes device-wide
        atomicAdd(bar, 1);
        while (__hip_atomic_load(bar, __ATOMIC_ACQUIRE, __HIP_MEMORY_SCOPE_AGENT) < NBLK) {
            __builtin_amdgcn_s_sleep(2);
        }
    }
    __syncthreads(); // all threads: scan complete + barrier passed (acquire inv done by t0)

    // ---------------- phase 2: sparse attention + out-projection ----------------
    const int qq = tid >> 5;
    const int lane = tid & 31;
    const int h = lane >> 2;
    const int s = lane & 3;
    const int bi = r0 + qq;
    const __half* kb = k + (size_t)b * NP1 * DM;
    const __half* vb = v + (size_t)b * NP1 * DM;

    float qf[16];
    {
        const float4* qr = (const float4*)(q + (size_t)bi * DM + h * DK);
#pragma unroll
        for (int e = 0; e < 4; ++e) {
            float4 t4 = qr[e];
            qf[e * 4 + 0] = t4.x * 0.25f; qf[e * 4 + 1] = t4.y * 0.25f;
            qf[e * 4 + 2] = t4.z * 0.25f; qf[e * 4 + 3] = t4.w * 0.25f;
        }
    }
    int M = mcount[qq]; if (M > CAND_PQ) M = CAND_PQ;
    if (qa[qq] <= 0.5f) M = 0; // dead query: patch only (l>0), output gated later
    const int pix = qx[qq], piy = qy[qq];

    float l = 0.f;
    float o[16];
#pragma unroll
    for (int e = 0; e < 16; ++e) o[e] = 0.f;

    if (s == 0) { // patch column: always allowed, no bias
        const uint4* kr = (const uint4*)(kb + (size_t)NN * DM + h * DK);
        uint4 ka = kr[0], kb4 = kr[1];
        const uint4* vr = (const uint4*)(vb + (size_t)NN * DM + h * DK);
        uint4 va = vr[0], vb4 = vr[1];
        float kf[16], vf[16];
        unpack8(ka, kf); unpack8(kb4, kf + 8);
        unpack8(va, vf); unpack8(vb4, vf + 8);
        float d = 0.f;
#pragma unroll
        for (int e = 0; e < 16; ++e) d = fmaf(qf[e], kf[e], d);
        float p = __expf(d);
        l += p;
#pragma unroll
        for (int e = 0; e < 16; ++e) o[e] = fmaf(p, vf[e], o[e]);
    }

    for (int t = s; t < M; t += 4) {
        int packed = cand[qq][t];
        int j = packed & 0xFFFF;
        const uint4* kr = (const uint4*)(kb + (size_t)j * DM + h * DK);
        uint4 ka = kr[0], kb4 = kr[1];
        const uint4* vr = (const uint4*)(vb + (size_t)j * DM + h * DK);
        uint4 va = vr[0], vb4 = vr[1];
        float kf[16], vf[16];
        unpack8(ka, kf); unpack8(kb4, kf + 8);
        unpack8(va, vf); unpack8(vb4, vf + 8);
        float d = 0.f;
#pragma unroll
        for (int e = 0; e < 16; ++e) d = fmaf(qf[e], kf[e], d);
        int pjx = (packed >> 16) & 0xFF;
        int pjy = (packed >> 24) & 0xFF;
        float bias = sbias[h * 81 + (pjx - pix + RWIN) * 9 + (pjy - piy + RWIN)];
        float p = __expf(d + bias);
        l += p;
#pragma unroll
        for (int e = 0; e < 16; ++e) o[e] = fmaf(p, vf[e], o[e]);
    }

    {
        const int prow = qq * 4 + s;
#pragma unroll
        for (int e = 0; e < 16; ++e) po[prow][h * DK + e] = o[e];
        pl[prow][h] = l;
    }
    __syncthreads();
    {
        const int c = tid & 127;
        const int g = tid >> 7;
        const int ch = c >> 4;
#pragma unroll
        for (int qn = 0; qn < 4; ++qn) {
            int qq2 = g * 4 + qn;
            float acc = 0.f, lh = 0.f;
#pragma unroll
            for (int ss = 0; ss < 4; ++ss) {
                acc += po[qq2 * 4 + ss][c];
                lh  += pl[qq2 * 4 + ss][ch];
            }
            srow[qq2][c] = acc / lh;
        }
    }
    __syncthreads();
    {
        const int oq = tid >> 5;
        const int c4 = lane;
        float ax = 0.f, ay = 0.f, az = 0.f, aw = 0.f;
#pragma unroll 8
        for (int kk = 0; kk < DM; ++kk) {
            float sv = srow[oq][kk];
            float4 w4 = *((const float4*)(Wo + kk * DM + c4 * 4));
            ax = fmaf(sv, w4.x, ax); ay = fmaf(sv, w4.y, ay);
            az = fmaf(sv, w4.z, az); aw = fmaf(sv, w4.w, aw);
        }
        float ga = sal[oq] > 0.5f ? 1.f : 0.f;
        float4 b4 = *((const float4*)(bo + c4 * 4));
        float4 r;
        r.x = (ax + b4.x) * ga; r.y = (ay + b4.y) * ga;
        r.z = (az + b4.z) * ga; r.w = (aw + b4.w) * ga;
        ((float4*)(out + (size_t)(r0 + oq) * DM))[c4] = r;
    }
}

extern "C" void kernel_launch(void* const* d_in, const int* in_sizes, int n_in,
                              void* d_out, int out_size, void* d_ws, size_t ws_size,
                              hipStream_t stream) {
    const float* z         = (const float*)d_in[0];
    const float* patch     = (const float*)d_in[1];
    const int*   positions = (const int*)d_in[2];
    const float* alive     = (const float*)d_in[3];
    const float* Wq        = (const float*)d_in[4];
    const float* bq        = (const float*)d_in[5];
    const float* Wk        = (const float*)d_in[6];
    const float* bk        = (const float*)d_in[7];
    const float* Wv        = (const float*)d_in[8];
    const float* bv        = (const float*)d_in[9];
    const float* Wo        = (const float*)d_in[10];
    const float* bo        = (const float*)d_in[11];
    const float* rel_bias  = (const float*)d_in[12];
    float* out = (float*)d_out;

    char* ws = (char*)d_ws;
    size_t off = 0;
    auto alloc = [&](size_t bytes) -> void* {
        void* p = ws + off;
        off += (bytes + 255) & ~(size_t)255;
        return p;
    };
    float*  q   = (float*)alloc((size_t)BB * NN * DM * 4);
    __half* k   = (__half*)alloc((size_t)BB * NP1 * DM * 2);
    __half* v   = (__half*)alloc((size_t)BB * NP1 * DM * 2);
    int*    bar = (int*)alloc(256);

    hipMemsetAsync(bar, 0, 8, stream);
    fused_kernel<<<NBLK, 256, 0, stream>>>(z, patch, Wq, bq, Wk, bk, Wv, bv,
                                           positions, alive, rel_bias, Wo, bo,
                                           q, k, v, bar, out);
}

// Round 12
// 131.277 us; speedup vs baseline: 1.4808x; 1.4808x over previous
//
#include <hip/hip_runtime.h>
#include <hip/hip_fp16.h>
#include <math.h>

#define BB 2
#define NN 2048
#define NP1 2049
#define DM 128
#define NH 8
#define DK 16
#define RWIN 4
#define GRID_W 64
#define QPB 8        /* queries per attn block */
#define CAND_PQ 160  /* per-query candidate cap; binom mean ~36, sd ~6 */

__device__ __forceinline__ void unpack8(uint4 r, float* f) {
    float2 t;
    t = __half22float2(*(const __half2*)&r.x); f[0] = t.x; f[1] = t.y;
    t = __half22float2(*(const __half2*)&r.y); f[2] = t.x; f[3] = t.y;
    t = __half22float2(*(const __half2*)&r.z); f[4] = t.x; f[5] = t.y;
    t = __half22float2(*(const __half2*)&r.w); f[6] = t.x; f[7] = t.y;
}

// ---------------- K/V projection only ----------------
// q never crosses the kernel boundary (each attn block computes its own
// queries' q in-block), so this kernel projects only K and V. 512 threads =
// 2 mats x 32 col-groups x 8 row-slots; 16 rows/block (each W float4 load
// feeds 2 rows -> FMA:VMEM 8:1). fp16 stores. Grid 257.

#define KV_ROWS 16

__global__ __launch_bounds__(512) void kv_kernel(
    const float* __restrict__ z, const float* __restrict__ patch,
    const float* __restrict__ Wk, const float* __restrict__ bk,
    const float* __restrict__ Wv, const float* __restrict__ bv,
    __half* __restrict__ k, __half* __restrict__ v) {
    __shared__ float zrow[KV_ROWS][DM];
    const int tid = threadIdx.x;
    const int mat = tid >> 8;          // 0=k 1=v, wave-uniform
    const int rem = tid & 255;
    const int cg = rem & 31;           // cols cg*4..cg*4+3
    const int rs = rem >> 5;           // rows rs, rs+8
    const int r0 = blockIdx.x * KV_ROWS;
    const int NROWS = BB * NP1;

    {   // stage 16 rows x 128 cols: 512 float4 tasks, one per thread
        int r = tid >> 5, c4 = tid & 31;
        int row = r0 + r;
        float4 val = make_float4(0.f, 0.f, 0.f, 0.f);
        if (row < NROWS) {
            int b = row / NP1, ti = row % NP1;
            const float* src = (ti < NN) ? (z + ((size_t)b * NN + ti) * DM)
                                         : (patch + (size_t)b * DM);
            val = ((const float4*)src)[c4];
        }
        *((float4*)&zrow[r][c4 * 4]) = val;
    }
    __syncthreads();

    const float* W    = mat ? Wv : Wk;
    const float* bias = mat ? bv : bk;

    float a0x = 0.f, a0y = 0.f, a0z = 0.f, a0w = 0.f;
    float a1x = 0.f, a1y = 0.f, a1z = 0.f, a1w = 0.f;
#pragma unroll 8
    for (int kk = 0; kk < DM; ++kk) {
        float4 w4 = *((const float4*)(W + kk * DM + cg * 4));
        float z0 = zrow[rs][kk];
        float z1 = zrow[rs + 8][kk];
        a0x = fmaf(z0, w4.x, a0x); a0y = fmaf(z0, w4.y, a0y);
        a0z = fmaf(z0, w4.z, a0z); a0w = fmaf(z0, w4.w, a0w);
        a1x = fmaf(z1, w4.x, a1x); a1y = fmaf(z1, w4.y, a1y);
        a1z = fmaf(z1, w4.z, a1z); a1w = fmaf(z1, w4.w, a1w);
    }
    float4 b4 = *((const float4*)(bias + cg * 4));
    __half* dst = mat ? v : k;
#pragma unroll
    for (int rr = 0; rr < 2; ++rr) {
        int row = r0 + rs + rr * 8;
        if (row >= NROWS) break;
        float rx = (rr ? a1x : a0x) + b4.x;
        float ry = (rr ? a1y : a0y) + b4.y;
        float rz = (rr ? a1z : a0z) + b4.z;
        float rw = (rr ? a1w : a0w) + b4.w;
        int b = row / NP1, ti = row % NP1;
        __half2 p0 = __floats2half2_rn(rx, ry);
        __half2 p1 = __floats2half2_rn(rz, rw);
        uint2 st; st.x = *(unsigned int*)&p0; st.y = *(unsigned int*)&p1;
        ((uint2*)(dst + ((size_t)b * NP1 + ti) * DM))[cg] = st;
    }
}

// ---------------- fused: in-block q-proj + neighbor scan + attention + out-proj ----------------
// R9 structure, plus: q for the block's 8 queries computed in-block (z rows
// staged to LDS, 128-kk float4 Wq loop -> qrow in LDS, 1/sqrt(dk) and bias
// folded). The neighbor scan follows immediately and overlaps the q-proj
// latency across waves. K/V gathers fp16 uint4. No-max softmax (logits
// O(0.3)). Dead queries: M=0, patch keeps l>0, output gated to 0.

__global__ __launch_bounds__(256) void attn_out_kernel(
    const float* __restrict__ z, const __half* __restrict__ k, const __half* __restrict__ v,
    const int* __restrict__ positions, const float* __restrict__ alive,
    const float* __restrict__ rel_bias, const float* __restrict__ Wq,
    const float* __restrict__ bq, const float* __restrict__ Wo,
    const float* __restrict__ bo, float* __restrict__ out) {
    const int tid = threadIdx.x;
    const int qq = tid >> 5;          // 0..7 query in group
    const int lane = tid & 31;
    const int h = lane >> 2;          // 0..7 head
    const int s = lane & 3;           // 0..3 key slot
    const int r0 = blockIdx.x * QPB;  // global query base (same batch: NN%QPB==0)
    const int b = r0 >> 11;

    __shared__ float sbias[NH * 81];
    __shared__ int   spx[QPB], spy[QPB];
    __shared__ float sal[QPB];
    __shared__ int   mcount[QPB];
    __shared__ int   cand[QPB][CAND_PQ];
    __shared__ float zq[QPB][DM];
    __shared__ float qrow[QPB][DM + 1];
    __shared__ float po[QPB * 4][DM + 1];
    __shared__ float pl[QPB * 4][NH + 1];
    __shared__ float srow[QPB][DM + 1];

    if (tid < QPB) {
        mcount[tid] = 0;
        int gbi = r0 + tid;
        spx[tid] = positions[gbi * 2 + 0];
        spy[tid] = positions[gbi * 2 + 1];
        sal[tid] = alive[gbi];
    }
    for (int t = tid; t < NH * 81; t += 256) sbias[t] = rel_bias[t];
    {   // stage the 8 z rows (coalesced float4; one per thread)
        int r = tid >> 5, c4 = tid & 31;
        const float* src = z + ((size_t)b * NN + ((r0 + r) & (NN - 1))) * DM;
        *((float4*)&zq[r][c4 * 4]) = ((const float4*)src)[c4];
    }
    __syncthreads();

    // in-block q projection: thread (qq, lane) -> cols lane*4..lane*4+3
    {
        float ax = 0.f, ay = 0.f, az = 0.f, aw = 0.f;
#pragma unroll 8
        for (int kk = 0; kk < DM; ++kk) {
            float sv = zq[qq][kk];
            float4 w4 = *((const float4*)(Wq + kk * DM + lane * 4));
            ax = fmaf(sv, w4.x, ax); ay = fmaf(sv, w4.y, ay);
            az = fmaf(sv, w4.z, az); aw = fmaf(sv, w4.w, aw);
        }
        float4 b4 = *((const float4*)(bq + lane * 4));
        qrow[qq][lane * 4 + 0] = (ax + b4.x) * 0.25f; // fold 1/sqrt(dk)
        qrow[qq][lane * 4 + 1] = (ay + b4.y) * 0.25f;
        qrow[qq][lane * 4 + 2] = (az + b4.z) * 0.25f;
        qrow[qq][lane * 4 + 3] = (aw + b4.w) * 0.25f;
    }

    int qx[QPB], qy[QPB], qi[QPB];
    float qa[QPB];
#pragma unroll
    for (int u = 0; u < QPB; ++u) {
        qx[u] = spx[u]; qy[u] = spy[u]; qa[u] = sal[u];
        qi[u] = (r0 + u) & (NN - 1);
    }

    // one scan over all agents, 8 query tests each (overlaps q-proj latency)
    {
        const int2* pb = (const int2*)(positions + (size_t)b * NN * 2);
        const float* ab = alive + (size_t)b * NN;
#pragma unroll
        for (int u = 0; u < NN / 256; ++u) {
            int j = u * 256 + tid;
            int2 pj = pb[j];
            float aj = ab[j];
            if (aj > 0.5f) {
                int packed = j | (pj.x << 16) | (pj.y << 24);
#pragma unroll
                for (int qn = 0; qn < QPB; ++qn) {
                    int dx = pj.x - qx[qn]; dx = dx < 0 ? -dx : dx;
                    int dy = pj.y - qy[qn]; dy = dy < 0 ? -dy : dy;
                    int ch = dx > dy ? dx : dy;
                    if (ch <= RWIN && j != qi[qn] && qa[qn] > 0.5f) {
                        int slot = atomicAdd(&mcount[qn], 1);
                        if (slot < CAND_PQ) cand[qn][slot] = packed;
                    }
                }
            }
        }
    }
    __syncthreads(); // qrow + cand complete

    const __half* kb = k + (size_t)b * NP1 * DM;
    const __half* vb = v + (size_t)b * NP1 * DM;

    float qf[16];
#pragma unroll
    for (int e = 0; e < 16; ++e) qf[e] = qrow[qq][h * DK + e];

    int M = mcount[qq]; if (M > CAND_PQ) M = CAND_PQ;
    if (qa[qq] <= 0.5f) M = 0;
    const int pix = qx[qq], piy = qy[qq];

    float l = 0.f;
    float o[16];
#pragma unroll
    for (int e = 0; e < 16; ++e) o[e] = 0.f;

    if (s == 0) { // patch column: always allowed, no bias; keeps l>0 for dead queries
        const uint4* kr = (const uint4*)(kb + (size_t)NN * DM + h * DK);
        uint4 ka = kr[0], kb4 = kr[1];
        const uint4* vr = (const uint4*)(vb + (size_t)NN * DM + h * DK);
        uint4 va = vr[0], vb4 = vr[1];
        float kf[16], vf[16];
        unpack8(ka, kf); unpack8(kb4, kf + 8);
        unpack8(va, vf); unpack8(vb4, vf + 8);
        float d = 0.f;
#pragma unroll
        for (int e = 0; e < 16; ++e) d = fmaf(qf[e], kf[e], d);
        float p = __expf(d);
        l += p;
#pragma unroll
        for (int e = 0; e < 16; ++e) o[e] = fmaf(p, vf[e], o[e]);
    }

    for (int t = s; t < M; t += 4) {
        int packed = cand[qq][t];
        int j = packed & 0xFFFF;
        const uint4* kr = (const uint4*)(kb + (size_t)j * DM + h * DK);
        uint4 ka = kr[0], kb4 = kr[1];
        const uint4* vr = (const uint4*)(vb + (size_t)j * DM + h * DK);
        uint4 va = vr[0], vb4 = vr[1];
        float kf[16], vf[16];
        unpack8(ka, kf); unpack8(kb4, kf + 8);
        unpack8(va, vf); unpack8(vb4, vf + 8);
        float d = 0.f;
#pragma unroll
        for (int e = 0; e < 16; ++e) d = fmaf(qf[e], kf[e], d);
        int pjx = (packed >> 16) & 0xFF;
        int pjy = (packed >> 24) & 0xFF;
        float bias = sbias[h * 81 + (pjx - pix + RWIN) * 9 + (pjy - piy + RWIN)];
        float p = __expf(d + bias);
        l += p;
#pragma unroll
        for (int e = 0; e < 16; ++e) o[e] = fmaf(p, vf[e], o[e]);
    }

    // reduction over the 4 key-slots via LDS
    {
        const int prow = qq * 4 + s;
#pragma unroll
        for (int e = 0; e < 16; ++e) po[prow][h * DK + e] = o[e];
        pl[prow][h] = l;
    }
    __syncthreads();
    {
        const int c = tid & 127;
        const int g = tid >> 7;
        const int ch = c >> 4;
#pragma unroll
        for (int qn = 0; qn < 4; ++qn) {
            int qq2 = g * 4 + qn;
            float acc = 0.f, lh = 0.f;
#pragma unroll
            for (int ss = 0; ss < 4; ++ss) {
                acc += po[qq2 * 4 + ss][c];
                lh  += pl[qq2 * 4 + ss][ch];
            }
            srow[qq2][c] = acc / lh;
        }
    }
    __syncthreads();

    // output projection: thread (oq = tid>>5, lane) -> cols lane*4..lane*4+3
    {
        const int oq = tid >> 5;
        float ax = 0.f, ay = 0.f, az = 0.f, aw = 0.f;
#pragma unroll 8
        for (int kk = 0; kk < DM; ++kk) {
            float sv = srow[oq][kk];
            float4 w4 = *((const float4*)(Wo + kk * DM + lane * 4));
            ax = fmaf(sv, w4.x, ax); ay = fmaf(sv, w4.y, ay);
            az = fmaf(sv, w4.z, az); aw = fmaf(sv, w4.w, aw);
        }
        float ga = sal[oq] > 0.5f ? 1.f : 0.f;
        float4 b4 = *((const float4*)(bo + lane * 4));
        float4 r;
        r.x = (ax + b4.x) * ga; r.y = (ay + b4.y) * ga;
        r.z = (az + b4.z) * ga; r.w = (aw + b4.w) * ga;
        ((float4*)(out + (size_t)(r0 + oq) * DM))[lane] = r;
    }
}

extern "C" void kernel_launch(void* const* d_in, const int* in_sizes, int n_in,
                              void* d_out, int out_size, void* d_ws, size_t ws_size,
                              hipStream_t stream) {
    const float* z         = (const float*)d_in[0];
    const float* patch     = (const float*)d_in[1];
    const int*   positions = (const int*)d_in[2];
    const float* alive     = (const float*)d_in[3];
    const float* Wq        = (const float*)d_in[4];
    const float* bq        = (const float*)d_in[5];
    const float* Wk        = (const float*)d_in[6];
    const float* bk        = (const float*)d_in[7];
    const float* Wv        = (const float*)d_in[8];
    const float* bv        = (const float*)d_in[9];
    const float* Wo        = (const float*)d_in[10];
    const float* bo        = (const float*)d_in[11];
    const float* rel_bias  = (const float*)d_in[12];
    float* out = (float*)d_out;

    char* ws = (char*)d_ws;
    size_t off = 0;
    auto alloc = [&](size_t bytes) -> void* {
        void* p = ws + off;
        off += (bytes + 255) & ~(size_t)255;
        return p;
    };
    __half* k = (__half*)alloc((size_t)BB * NP1 * DM * 2);
    __half* v = (__half*)alloc((size_t)BB * NP1 * DM * 2);

    kv_kernel<<<(BB * NP1 + KV_ROWS - 1) / KV_ROWS, 512, 0, stream>>>(z, patch, Wk, bk, Wv, bv, k, v);
    attn_out_kernel<<<(BB * NN) / QPB, 256, 0, stream>>>(z, k, v, positions, alive, rel_bias, Wq, bq, Wo, bo, out);
}

// Round 14
// 122.563 us; speedup vs baseline: 1.5861x; 1.0711x over previous
//
#include <hip/hip_runtime.h>
#include <hip/hip_fp16.h>
#include <math.h>

#define BB 2
#define NN 2048
#define NP1 2049
#define DM 128
#define NH 8
#define DK 16
#define RWIN 4
#define GRID_W 64
#define QPB 4        /* queries per attn block */
#define CAND_PQ 160  /* per-query candidate cap; binom mean ~36, sd ~6 */

__device__ __forceinline__ void unpack8(uint4 r, float* f) {
    float2 t;
    t = __half22float2(*(const __half2*)&r.x); f[0] = t.x; f[1] = t.y;
    t = __half22float2(*(const __half2*)&r.y); f[2] = t.x; f[3] = t.y;
    t = __half22float2(*(const __half2*)&r.z); f[4] = t.x; f[5] = t.y;
    t = __half22float2(*(const __half2*)&r.w); f[6] = t.x; f[7] = t.y;
}

// ---------------- QKV projection (R9's kernel, unchanged) ----------------
// 384 threads = 3 mats x (32 col-groups x 4 row-slots). Thread owns 4
// consecutive output columns (float4 W loads) and rows rs, rs+4.
// K/V stored fp16; q stays fp32.

#define QKV_ROWS 8

__global__ __launch_bounds__(384) void qkv_kernel(
    const float* __restrict__ z, const float* __restrict__ patch,
    const float* __restrict__ Wq, const float* __restrict__ bq,
    const float* __restrict__ Wk, const float* __restrict__ bk,
    const float* __restrict__ Wv, const float* __restrict__ bv,
    float* __restrict__ q, __half* __restrict__ k, __half* __restrict__ v) {
    __shared__ float zrow[QKV_ROWS][DM];
    const int tid = threadIdx.x;
    const int mat = tid >> 7;          // 0=q 1=k 2=v, wave-uniform
    const int rem = tid & 127;
    const int cg = rem & 31;           // cols cg*4..cg*4+3
    const int rs = rem >> 5;           // rows rs, rs+4
    const int r0 = blockIdx.x * QKV_ROWS;
    const int NROWS = BB * NP1;

    if (tid < QKV_ROWS * DM / 4) {
        int r = tid >> 5, q4 = tid & 31;
        int row = r0 + r;
        float4 val = make_float4(0.f, 0.f, 0.f, 0.f);
        if (row < NROWS) {
            int b = row / NP1, ti = row % NP1;
            const float* src = (ti < NN) ? (z + ((size_t)b * NN + ti) * DM)
                                         : (patch + (size_t)b * DM);
            val = ((const float4*)src)[q4];
        }
        *((float4*)&zrow[r][q4 * 4]) = val;
    }
    __syncthreads();

    const float* W    = (mat == 0) ? Wq : (mat == 1) ? Wk : Wv;
    const float* bias = (mat == 0) ? bq : (mat == 1) ? bk : bv;

    float a0x = 0.f, a0y = 0.f, a0z = 0.f, a0w = 0.f;
    float a1x = 0.f, a1y = 0.f, a1z = 0.f, a1w = 0.f;
#pragma unroll 8
    for (int kk = 0; kk < DM; ++kk) {
        float4 w4 = *((const float4*)(W + kk * DM + cg * 4));
        float z0 = zrow[rs][kk];
        float z1 = zrow[rs + 4][kk];
        a0x = fmaf(z0, w4.x, a0x); a0y = fmaf(z0, w4.y, a0y);
        a0z = fmaf(z0, w4.z, a0z); a0w = fmaf(z0, w4.w, a0w);
        a1x = fmaf(z1, w4.x, a1x); a1y = fmaf(z1, w4.y, a1y);
        a1z = fmaf(z1, w4.z, a1z); a1w = fmaf(z1, w4.w, a1w);
    }
    float4 b4 = *((const float4*)(bias + cg * 4));
    float4 o0 = make_float4(a0x + b4.x, a0y + b4.y, a0z + b4.z, a0w + b4.w);
    float4 o1 = make_float4(a1x + b4.x, a1y + b4.y, a1z + b4.z, a1w + b4.w);

#pragma unroll
    for (int rr = 0; rr < 2; ++rr) {
        int row = r0 + rs + rr * 4;
        if (row >= NROWS) break;
        float4 val = rr ? o1 : o0;
        int b = row / NP1, ti = row % NP1;
        if (mat == 0) {
            if (ti < NN) ((float4*)(q + ((size_t)b * NN + ti) * DM))[cg] = val;
        } else {
            __half2 p0 = __floats2half2_rn(val.x, val.y);
            __half2 p1 = __floats2half2_rn(val.z, val.w);
            uint2 st;
            st.x = *(unsigned int*)&p0;
            st.y = *(unsigned int*)&p1;
            __half* dst = ((mat == 1) ? k : v) + ((size_t)b * NP1 + ti) * DM;
            ((uint2*)dst)[cg] = st;
        }
    }
}

// ---------------- fused: 4-query scan + sparse attention + out-proj ----------------
// TLP-doubled R9: grid 1024 blocks (16 waves/CU), 256 threads =
// 4 queries x 8 heads x 8 key-slots -> keys/thread ~4.6 (half the serial
// gather chain of R9). fp16 K/V uint4 gathers. Out-projection: one wave per
// query, kk split across lane halves, combined via shfl_xor(32) to keep
// float4 Wo loads. No-max softmax (logits O(0.3), exp-safe). Dead queries:
// scan skips them (M=0), patch keeps l>0, output gated to 0.

__global__ __launch_bounds__(256) void attn_out_kernel(
    const float* __restrict__ q, const __half* __restrict__ k, const __half* __restrict__ v,
    const int* __restrict__ positions, const float* __restrict__ alive,
    const float* __restrict__ rel_bias, const float* __restrict__ Wo,
    const float* __restrict__ bo, float* __restrict__ out) {
    const int tid = threadIdx.x;
    const int qq = tid >> 6;          // 0..3 query in group
    const int l6 = tid & 63;
    const int h = l6 >> 3;            // 0..7 head
    const int s = l6 & 7;             // 0..7 key slot
    const int r0 = blockIdx.x * QPB;  // global query base (same batch: NN%QPB==0)
    const int b = r0 >> 11;
    const int bi = r0 + qq;

    __shared__ float sbias[NH * 81];
    __shared__ int   spx[QPB], spy[QPB];
    __shared__ float sal[QPB];
    __shared__ int   mcount[QPB];
    __shared__ int   cand[QPB][CAND_PQ];
    __shared__ float po[QPB * 8][DM + 1];
    __shared__ float pl[QPB * 8][NH + 1];
    __shared__ float srow[QPB][DM + 1];

    if (tid < QPB) {
        mcount[tid] = 0;
        int gbi = r0 + tid;
        spx[tid] = positions[gbi * 2 + 0];
        spy[tid] = positions[gbi * 2 + 1];
        sal[tid] = alive[gbi];
    }
    for (int t = tid; t < NH * 81; t += 256) sbias[t] = rel_bias[t];

    const __half* kb = k + (size_t)b * NP1 * DM;
    const __half* vb = v + (size_t)b * NP1 * DM;

    // q segment for (query qq, head h), pre-scaled by 1/sqrt(dk)
    float qf[16];
    {
        const float4* qr = (const float4*)(q + (size_t)bi * DM + h * DK);
#pragma unroll
        for (int e = 0; e < 4; ++e) {
            float4 t4 = qr[e];
            qf[e * 4 + 0] = t4.x * 0.25f; qf[e * 4 + 1] = t4.y * 0.25f;
            qf[e * 4 + 2] = t4.z * 0.25f; qf[e * 4 + 3] = t4.w * 0.25f;
        }
    }

    __syncthreads(); // spos/sal/mcount/sbias visible

    int qx[QPB], qy[QPB], qi[QPB];
    float qa[QPB];
#pragma unroll
    for (int u = 0; u < QPB; ++u) {
        qx[u] = spx[u]; qy[u] = spy[u]; qa[u] = sal[u];
        qi[u] = (r0 + u) & (NN - 1);
    }

    // one scan over all agents, 4 query tests each
    {
        const int2* pb = (const int2*)(positions + (size_t)b * NN * 2);
        const float* ab = alive + (size_t)b * NN;
#pragma unroll
        for (int u = 0; u < NN / 256; ++u) {
            int j = u * 256 + tid;
            int2 pj = pb[j];
            float aj = ab[j];
            if (aj > 0.5f) {
                int packed = j | (pj.x << 16) | (pj.y << 24);
#pragma unroll
                for (int qn = 0; qn < QPB; ++qn) {
                    int dx = pj.x - qx[qn]; dx = dx < 0 ? -dx : dx;
                    int dy = pj.y - qy[qn]; dy = dy < 0 ? -dy : dy;
                    int ch = dx > dy ? dx : dy;
                    if (ch <= RWIN && j != qi[qn] && qa[qn] > 0.5f) {
                        int slot = atomicAdd(&mcount[qn], 1);
                        if (slot < CAND_PQ) cand[qn][slot] = packed;
                    }
                }
            }
        }
    }
    __syncthreads();
    int M = mcount[qq]; if (M > CAND_PQ) M = CAND_PQ;
    const int pix = qx[qq], piy = qy[qq];

    float l = 0.f;
    float o[16];
#pragma unroll
    for (int e = 0; e < 16; ++e) o[e] = 0.f;

    if (s == 0) { // patch column: always allowed, no bias; keeps l>0 for dead queries
        const uint4* kr = (const uint4*)(kb + (size_t)NN * DM + h * DK);
        uint4 ka = kr[0], kb4 = kr[1];
        const uint4* vr = (const uint4*)(vb + (size_t)NN * DM + h * DK);
        uint4 va = vr[0], vb4 = vr[1];
        float kf[16], vf[16];
        unpack8(ka, kf); unpack8(kb4, kf + 8);
        unpack8(va, vf); unpack8(vb4, vf + 8);
        float d = 0.f;
#pragma unroll
        for (int e = 0; e < 16; ++e) d = fmaf(qf[e], kf[e], d);
        float p = __expf(d);
        l += p;
#pragma unroll
        for (int e = 0; e < 16; ++e) o[e] = fmaf(p, vf[e], o[e]);
    }

    for (int t = s; t < M; t += 8) {
        int packed = cand[qq][t];
        int j = packed & 0xFFFF;
        const uint4* kr = (const uint4*)(kb + (size_t)j * DM + h * DK);
        uint4 ka = kr[0], kb4 = kr[1];
        const uint4* vr = (const uint4*)(vb + (size_t)j * DM + h * DK);
        uint4 va = vr[0], vb4 = vr[1];
        float kf[16], vf[16];
        unpack8(ka, kf); unpack8(kb4, kf + 8);
        unpack8(va, vf); unpack8(vb4, vf + 8);
        float d = 0.f;
#pragma unroll
        for (int e = 0; e < 16; ++e) d = fmaf(qf[e], kf[e], d);
        int pjx = (packed >> 16) & 0xFF;
        int pjy = (packed >> 24) & 0xFF;
        float bias = sbias[h * 81 + (pjx - pix + RWIN) * 9 + (pjy - piy + RWIN)];
        float p = __expf(d + bias);
        l += p;
#pragma unroll
        for (int e = 0; e < 16; ++e) o[e] = fmaf(p, vf[e], o[e]);
    }

    // reduction over the 8 key-slots via LDS
    {
        const int prow = qq * 8 + s;
#pragma unroll
        for (int e = 0; e < 16; ++e) po[prow][h * DK + e] = o[e];
        pl[prow][h] = l;
    }
    __syncthreads();
    {
        const int c = tid & 127;
        const int g = tid >> 7; // 0/1 -> queries g*2..g*2+1
        const int ch = c >> 4;
#pragma unroll
        for (int qn = 0; qn < 2; ++qn) {
            int qq2 = g * 2 + qn;
            float acc = 0.f, lh = 0.f;
#pragma unroll
            for (int ss = 0; ss < 8; ++ss) {
                acc += po[qq2 * 8 + ss][c];
                lh  += pl[qq2 * 8 + ss][ch];
            }
            srow[qq2][c] = acc / lh;
        }
    }
    __syncthreads();

    // output projection: wave w handles query w; lanes split kk in halves
    // (half = l6>>5, m = l6&31 -> cols m*4..m*4+3), combine via shfl_xor(32).
    {
        const int oq = qq;
        const int half = l6 >> 5;
        const int m = l6 & 31;
        const float* Wb = Wo + (size_t)half * 64 * DM + m * 4;
        const float* sr = &srow[oq][half * 64];
        float ax = 0.f, ay = 0.f, az = 0.f, aw = 0.f;
#pragma unroll 16
        for (int kk = 0; kk < 64; ++kk) {
            float sv = sr[kk];
            float4 w4 = *((const float4*)(Wb + (size_t)kk * DM));
            ax = fmaf(sv, w4.x, ax); ay = fmaf(sv, w4.y, ay);
            az = fmaf(sv, w4.z, az); aw = fmaf(sv, w4.w, aw);
        }
        ax += __shfl_xor(ax, 32, 64); ay += __shfl_xor(ay, 32, 64);
        az += __shfl_xor(az, 32, 64); aw += __shfl_xor(aw, 32, 64);
        if (half == 0) {
            float ga = sal[oq] > 0.5f ? 1.f : 0.f;
            float4 b4 = *((const float4*)(bo + m * 4));
            float4 r;
            r.x = (ax + b4.x) * ga; r.y = (ay + b4.y) * ga;
            r.z = (az + b4.z) * ga; r.w = (aw + b4.w) * ga;
            ((float4*)(out + (size_t)(r0 + oq) * DM))[m] = r;
        }
    }
}

extern "C" void kernel_launch(void* const* d_in, const int* in_sizes, int n_in,
                              void* d_out, int out_size, void* d_ws, size_t ws_size,
                              hipStream_t stream) {
    const float* z         = (const float*)d_in[0];
    const float* patch     = (const float*)d_in[1];
    const int*   positions = (const int*)d_in[2];
    const float* alive     = (const float*)d_in[3];
    const float* Wq        = (const float*)d_in[4];
    const float* bq        = (const float*)d_in[5];
    const float* Wk        = (const float*)d_in[6];
    const float* bk        = (const float*)d_in[7];
    const float* Wv        = (const float*)d_in[8];
    const float* bv        = (const float*)d_in[9];
    const float* Wo        = (const float*)d_in[10];
    const float* bo        = (const float*)d_in[11];
    const float* rel_bias  = (const float*)d_in[12];
    float* out = (float*)d_out;

    char* ws = (char*)d_ws;
    size_t off = 0;
    auto alloc = [&](size_t bytes) -> void* {
        void* p = ws + off;
        off += (bytes + 255) & ~(size_t)255;
        return p;
    };
    float*  q = (float*)alloc((size_t)BB * NN * DM * 4);
    __half* k = (__half*)alloc((size_t)BB * NP1 * DM * 2);
    __half* v = (__half*)alloc((size_t)BB * NP1 * DM * 2);

    qkv_kernel<<<(BB * NP1 + QKV_ROWS - 1) / QKV_ROWS, 384, 0, stream>>>(z, patch, Wq, bq, Wk, bk, Wv, bv, q, k, v);
    attn_out_kernel<<<(BB * NN) / QPB, 256, 0, stream>>>(q, k, v, positions, alive, rel_bias, Wo, bo, out);
}